// Round 3
// baseline (134.055 us; speedup 1.0000x reference)
//
#include <hip/hip_runtime.h>
#include <hip/hip_bf16.h>

typedef __attribute__((ext_vector_type(8))) short bfx8;
typedef __attribute__((ext_vector_type(4))) short bfx4;
typedef __attribute__((ext_vector_type(4))) float fx4;

static __device__ __forceinline__ short f2bf(float f) {
  union { float f; unsigned u; } v; v.f = f;
  unsigned r = v.u + 0x7fffu + ((v.u >> 16) & 1u);
  return (short)(r >> 16);
}

static __device__ __forceinline__ void gld16(const void* g, void* l) {
  __builtin_amdgcn_global_load_lds(
      (const __attribute__((address_space(1))) void*)g,
      (__attribute__((address_space(3))) void*)l, 16, 0, 0);
}

constexpr int Bz = 8, Sq = 512, Em = 1024, Hn = 16, Dh = 64;
constexpr int Mrows = Bz * Sq;             // 4096
constexpr size_t NE = (size_t)Mrows * Em;  // 4,194,304
constexpr size_t WE = (size_t)Em * Em;     // 1,048,576

// ---------------- f32 -> bf16 pre-convert (memory-bound) ----------------
__global__ __launch_bounds__(256) void convert_kernel(
    const float* __restrict__ q, const float* __restrict__ k,
    const float* __restrict__ v,
    const float* __restrict__ Wq, const float* __restrict__ Wk,
    const float* __restrict__ Wv, const float* __restrict__ Wo,
    short* __restrict__ qx, short* __restrict__ kx, short* __restrict__ vx,
    short* __restrict__ wqb, short* __restrict__ wkb,
    short* __restrict__ wvb, short* __restrict__ wob)
{
  const int seg = blockIdx.y;
  const float* src; short* dst; size_t n;
  switch (seg) {
    case 0: src = q;  dst = qx;  n = NE; break;
    case 1: src = k;  dst = kx;  n = NE; break;
    case 2: src = v;  dst = vx;  n = NE; break;
    case 3: src = Wq; dst = wqb; n = WE; break;
    case 4: src = Wk; dst = wkb; n = WE; break;
    case 5: src = Wv; dst = wvb; n = WE; break;
    default: src = Wo; dst = wob; n = WE; break;
  }
  const size_t i = ((size_t)blockIdx.x * 256 + threadIdx.x) * 8;
  if (i >= n) return;
  fx4 a = *(const fx4*)(src + i);
  fx4 b = *(const fx4*)(src + i + 4);
  bfx8 o = { f2bf(a[0]), f2bf(a[1]), f2bf(a[2]), f2bf(a[3]),
             f2bf(b[0]), f2bf(b[1]), f2bf(b[2]), f2bf(b[3]) };
  *(bfx8*)(dst + i) = o;
}

// ---------------- m97-structure bf16 GEMM, C^T orientation ----------------
// A-operand = W rows (output features nn), B-operand = X rows (tokens m).
// Accumulator: lane fr -> token m, (fq*4+i) -> 4 consecutive nn  => vector epilogue.
// 128x128 tile, BK=32, 4 waves (2x2), global_load_lds(16B), linear LDS [128][32].

// QKV projection: dst = X @ W^T + bias + pe, bf16 scatter.
//   z==0 (Q), z==1 (K): dst layout [B,H,S,Dh]
//   z==2 (V):           dst layout [B,H,Dh,S]  (pre-transposed for attn PV)
__global__ __launch_bounds__(256) void gemm_qkv_bf16(
    const short* __restrict__ qx, const short* __restrict__ kx,
    const short* __restrict__ vx,
    const short* __restrict__ Wqb, const short* __restrict__ Wkb,
    const short* __restrict__ Wvb,
    const float* __restrict__ bq, const float* __restrict__ bk,
    const float* __restrict__ bv,
    const float* __restrict__ pos,
    short* __restrict__ qb, short* __restrict__ kb, short* __restrict__ vb)
{
  __shared__ short As[128 * 32];   // W tile  (nn rows)
  __shared__ short Bs[128 * 32];   // X tile  (m rows)
  const int z = blockIdx.z;
  const short* X = (z == 0) ? qx : (z == 1) ? kx : vx;
  const short* W = (z == 0) ? Wqb : (z == 1) ? Wkb : Wvb;
  const float* bias = (z == 0) ? bq : (z == 1) ? bk : bv;
  short* dst = (z == 0) ? qb : (z == 1) ? kb : vb;

  const int n0 = blockIdx.x * 128;   // over Em
  const int m0 = blockIdx.y * 128;   // over Mrows
  const int t = threadIdx.x, lane = t & 63, wave = t >> 6;
  const int wr = wave >> 1, wc = wave & 1;
  const int fr = lane & 15, fq = lane >> 4;

  const int r0 = t >> 2, o0 = (t & 3) * 8;
  const int r1 = r0 + 64;
  short* lA0 = As + wave * 512;
  short* lA1 = As + 2048 + wave * 512;
  short* lB0 = Bs + wave * 512;
  short* lB1 = Bs + 2048 + wave * 512;

  fx4 acc[4][4] = {};

  for (int k0 = 0; k0 < Em; k0 += 32) {
    gld16(W + (size_t)(n0 + r0) * Em + k0 + o0, lA0);
    gld16(W + (size_t)(n0 + r1) * Em + k0 + o0, lA1);
    gld16(X + (size_t)(m0 + r0) * Em + k0 + o0, lB0);
    gld16(X + (size_t)(m0 + r1) * Em + k0 + o0, lB1);
    __syncthreads();

    bfx8 af[4], bf[4];
#pragma unroll
    for (int u = 0; u < 4; ++u)
      af[u] = *(const bfx8*)&As[(wr * 64 + u * 16 + fr) * 32 + fq * 8];
#pragma unroll
    for (int v = 0; v < 4; ++v)
      bf[v] = *(const bfx8*)&Bs[(wc * 64 + v * 16 + fr) * 32 + fq * 8];
#pragma unroll
    for (int u = 0; u < 4; ++u)
#pragma unroll
      for (int v = 0; v < 4; ++v)
        acc[u][v] = __builtin_amdgcn_mfma_f32_16x16x32_bf16(af[u], bf[v], acc[u][v], 0, 0, 0);
    __syncthreads();
  }

  // epilogue: D[nn][m]; lane holds 4 consecutive nn at fixed token m
#pragma unroll
  for (int u = 0; u < 4; ++u) {
    const int nn = n0 + wr * 64 + u * 16 + fq * 4;   // multiple of 4
    const int h = nn >> 6, d = nn & 63;
    const fx4 bb = *(const fx4*)&bias[nn];
#pragma unroll
    for (int v = 0; v < 4; ++v) {
      const int m = m0 + wc * 64 + v * 16 + fr;
      const int s = m & (Sq - 1), b = m >> 9;
      const fx4 pe = *(const fx4*)&pos[(size_t)s * Em + nn];
      const fx4 a = acc[u][v];
      if (z < 2) {
        bfx4 o = { f2bf(a[0] + bb[0] + pe[0]), f2bf(a[1] + bb[1] + pe[1]),
                   f2bf(a[2] + bb[2] + pe[2]), f2bf(a[3] + bb[3] + pe[3]) };
        *(bfx4*)&dst[(((size_t)b * Hn + h) * Sq + s) * Dh + d] = o;
      } else {
        // V transposed: [B,H,Dh,S]
        const size_t tb = ((size_t)b * Hn + h) * Dh;
#pragma unroll
        for (int i = 0; i < 4; ++i)
          dst[(tb + d + i) * Sq + s] = f2bf(a[i] + bb[i] + pe[i]);
      }
    }
  }
}

// output projection: out = wv @ Wo^T + bo  (f32 out, vector stores)
__global__ __launch_bounds__(256) void gemm_out_bf16(
    const short* __restrict__ wv, const short* __restrict__ Wob,
    const float* __restrict__ bo, float* __restrict__ out)
{
  __shared__ short As[128 * 32];
  __shared__ short Bs[128 * 32];

  const int n0 = blockIdx.x * 128;
  const int m0 = blockIdx.y * 128;
  const int t = threadIdx.x, lane = t & 63, wave = t >> 6;
  const int wr = wave >> 1, wc = wave & 1;
  const int fr = lane & 15, fq = lane >> 4;

  const int r0 = t >> 2, o0 = (t & 3) * 8;
  const int r1 = r0 + 64;
  short* lA0 = As + wave * 512;
  short* lA1 = As + 2048 + wave * 512;
  short* lB0 = Bs + wave * 512;
  short* lB1 = Bs + 2048 + wave * 512;

  fx4 acc[4][4] = {};

  for (int k0 = 0; k0 < Em; k0 += 32) {
    gld16(Wob + (size_t)(n0 + r0) * Em + k0 + o0, lA0);
    gld16(Wob + (size_t)(n0 + r1) * Em + k0 + o0, lA1);
    gld16(wv + (size_t)(m0 + r0) * Em + k0 + o0, lB0);
    gld16(wv + (size_t)(m0 + r1) * Em + k0 + o0, lB1);
    __syncthreads();

    bfx8 af[4], bf[4];
#pragma unroll
    for (int u = 0; u < 4; ++u)
      af[u] = *(const bfx8*)&As[(wr * 64 + u * 16 + fr) * 32 + fq * 8];
#pragma unroll
    for (int v = 0; v < 4; ++v)
      bf[v] = *(const bfx8*)&Bs[(wc * 64 + v * 16 + fr) * 32 + fq * 8];
#pragma unroll
    for (int u = 0; u < 4; ++u)
#pragma unroll
      for (int v = 0; v < 4; ++v)
        acc[u][v] = __builtin_amdgcn_mfma_f32_16x16x32_bf16(af[u], bf[v], acc[u][v], 0, 0, 0);
    __syncthreads();
  }

#pragma unroll
  for (int u = 0; u < 4; ++u) {
    const int nn = n0 + wr * 64 + u * 16 + fq * 4;
    const fx4 bb = *(const fx4*)&bo[nn];
#pragma unroll
    for (int v = 0; v < 4; ++v) {
      const int m = m0 + wc * 64 + v * 16 + fr;
      fx4 val = acc[u][v];
      val[0] += bb[0]; val[1] += bb[1]; val[2] += bb[2]; val[3] += bb[3];
      *(fx4*)&out[(size_t)m * Em + nn] = val;
    }
  }
}

// ---------------- Attention ----------------
// kb: [B,H,S,Dh]; vb: [B,H,Dh,S] (pre-transposed) -> V staging == K staging.
constexpr int KVB = 64, LDK = 72;

__global__ __launch_bounds__(256) void attn_kernel(
    const short* __restrict__ qb, const short* __restrict__ kb,
    const short* __restrict__ vb, short* __restrict__ wv)
{
  __shared__ short Ks[KVB * LDK];   // K tile [kv][d]
  __shared__ short Vt[Dh * LDK];    // V^T tile [d][kv]
  __shared__ short Ps[4][16 * LDK];

  const int bh = blockIdx.x;
  const int qt = blockIdx.y;
  const int t = threadIdx.x, lane = t & 63, wave = t >> 6;
  const int fr = lane & 15, fq = lane >> 4;

  const size_t base = (size_t)bh * Sq * Dh;
  const int q0 = qt * 64 + wave * 16;

  bfx8 qf[2];
  {
    const short* qp = qb + base + (size_t)(q0 + fr) * Dh;
    qf[0] = *(const bfx8*)(qp + fq * 8);
    qf[1] = *(const bfx8*)(qp + 32 + fq * 8);
  }

  float mrow[4] = { -1e30f, -1e30f, -1e30f, -1e30f };
  float lrow[4] = { 0.f, 0.f, 0.f, 0.f };
  fx4 oacc[4] = {};

  const int kr = t >> 2, kc = (t & 3) * 16;

  for (int kv0 = 0; kv0 < Sq; kv0 += KVB) {
    {  // stage K [64 kv][64 d]
      const short* kp = kb + base + (size_t)(kv0 + kr) * Dh + kc;
      bfx8 u0 = *(const bfx8*)kp;
      bfx8 u1 = *(const bfx8*)(kp + 8);
      *(bfx8*)&Ks[kr * LDK + kc] = u0;
      *(bfx8*)&Ks[kr * LDK + kc + 8] = u1;
    }
    {  // stage V^T [64 d][64 kv] straight from transposed global
      const short* vp = vb + base + (size_t)kr * Sq + kv0 + kc;
      bfx8 u0 = *(const bfx8*)vp;
      bfx8 u1 = *(const bfx8*)(vp + 8);
      *(bfx8*)&Vt[kr * LDK + kc] = u0;
      *(bfx8*)&Vt[kr * LDK + kc + 8] = u1;
    }
    __syncthreads();

    fx4 sa[4] = {};
#pragma unroll
    for (int nf = 0; nf < 4; ++nf) {
#pragma unroll
      for (int ks = 0; ks < 2; ++ks) {
        bfx8 kf = *(const bfx8*)&Ks[(nf * 16 + fr) * LDK + ks * 32 + fq * 8];
        sa[nf] = __builtin_amdgcn_mfma_f32_16x16x32_bf16(qf[ks], kf, sa[nf], 0, 0, 0);
      }
    }

#pragma unroll
    for (int i = 0; i < 4; ++i) {
      float mx = fmaxf(fmaxf(sa[0][i], sa[1][i]), fmaxf(sa[2][i], sa[3][i]));
      mx = fmaxf(mx, __shfl_xor(mx, 1));
      mx = fmaxf(mx, __shfl_xor(mx, 2));
      mx = fmaxf(mx, __shfl_xor(mx, 4));
      mx = fmaxf(mx, __shfl_xor(mx, 8));
      mx *= 0.125f;
      const float mn = fmaxf(mrow[i], mx);
      const float alpha = __expf(mrow[i] - mn);
      mrow[i] = mn;
      float rs = 0.f;
#pragma unroll
      for (int nf = 0; nf < 4; ++nf) {
        const float p = __expf(sa[nf][i] * 0.125f - mn);
        rs += p;
        Ps[wave][(fq * 4 + i) * LDK + nf * 16 + fr] = f2bf(p);
      }
      rs += __shfl_xor(rs, 1);
      rs += __shfl_xor(rs, 2);
      rs += __shfl_xor(rs, 4);
      rs += __shfl_xor(rs, 8);
      lrow[i] = lrow[i] * alpha + rs;
#pragma unroll
      for (int df = 0; df < 4; ++df) oacc[df][i] *= alpha;
    }
    __syncthreads();

    bfx8 pf[2];
    pf[0] = *(const bfx8*)&Ps[wave][fr * LDK + fq * 8];
    pf[1] = *(const bfx8*)&Ps[wave][fr * LDK + 32 + fq * 8];
#pragma unroll
    for (int df = 0; df < 4; ++df) {
#pragma unroll
      for (int ks = 0; ks < 2; ++ks) {
        bfx8 vf = *(const bfx8*)&Vt[(df * 16 + fr) * LDK + ks * 32 + fq * 8];
        oacc[df] = __builtin_amdgcn_mfma_f32_16x16x32_bf16(pf[ks], vf, oacc[df], 0, 0, 0);
      }
    }
    __syncthreads();
  }

  const int b = bh >> 4, h = bh & 15;
#pragma unroll
  for (int df = 0; df < 4; ++df) {
    const int d = df * 16 + fr;
#pragma unroll
    for (int i = 0; i < 4; ++i) {
      const int qrow = q0 + fq * 4 + i;
      const float o = oacc[df][i] / lrow[i];
      wv[((size_t)b * Sq + qrow) * Em + h * Dh + d] = f2bf(o);
    }
  }
}

extern "C" void kernel_launch(void* const* d_in, const int* in_sizes, int n_in,
                              void* d_out, int out_size, void* d_ws, size_t ws_size,
                              hipStream_t stream) {
  (void)in_sizes; (void)n_in; (void)out_size; (void)ws_size;
  const float* query = (const float*)d_in[0];
  const float* key   = (const float*)d_in[1];
  const float* value = (const float*)d_in[2];
  const float* Wq = (const float*)d_in[3];
  const float* bq = (const float*)d_in[4];
  const float* Wk = (const float*)d_in[5];
  const float* bk = (const float*)d_in[6];
  const float* Wv = (const float*)d_in[7];
  const float* bv = (const float*)d_in[8];
  const float* Wo = (const float*)d_in[9];
  const float* bo = (const float*)d_in[10];
  const float* pos = (const float*)d_in[11];

  short* qx = (short*)d_ws;
  short* kx = qx + NE;
  short* vx = kx + NE;
  short* Wqb = vx + NE;
  short* Wkb = Wqb + WE;
  short* Wvb = Wkb + WE;
  short* Wob = Wvb + WE;
  short* qb = Wob + WE;
  short* wv = qx;                 // alias: qx dead after gemm_qkv
  short* kb = (short*)d_out;      // d_out scratch, overwritten by gemm_out
  short* vb = kb + NE;            // [B,H,Dh,S]

  convert_kernel<<<dim3(2048, 7), 256, 0, stream>>>(
      query, key, value, Wq, Wk, Wv, Wo, qx, kx, vx, Wqb, Wkb, Wvb, Wob);
  gemm_qkv_bf16<<<dim3(Em / 128, Mrows / 128, 3), 256, 0, stream>>>(
      qx, kx, vx, Wqb, Wkb, Wvb, bq, bk, bv, pos, qb, kb, vb);
  attn_kernel<<<dim3(Bz * Hn, Sq / 64), 256, 0, stream>>>(qb, kb, vb, wv);
  gemm_out_bf16<<<dim3(Em / 128, Mrows / 128), 256, 0, stream>>>(
      wv, Wob, bo, (float*)d_out);
}

// Round 4
// 131.375 us; speedup vs baseline: 1.0204x; 1.0204x over previous
//
#include <hip/hip_runtime.h>
#include <hip/hip_bf16.h>

typedef __attribute__((ext_vector_type(8))) short bfx8;
typedef __attribute__((ext_vector_type(4))) short bfx4;
typedef __attribute__((ext_vector_type(4))) float fx4;

static __device__ __forceinline__ short f2bf(float f) {
  union { float f; unsigned u; } v; v.f = f;
  unsigned r = v.u + 0x7fffu + ((v.u >> 16) & 1u);
  return (short)(r >> 16);
}

static __device__ __forceinline__ void gld16(const void* g, void* l) {
  __builtin_amdgcn_global_load_lds(
      (const __attribute__((address_space(1))) void*)g,
      (__attribute__((address_space(3))) void*)l, 16, 0, 0);
}

constexpr int Bz = 8, Sq = 512, Em = 1024, Hn = 16, Dh = 64;
constexpr int Mrows = Bz * Sq;             // 4096
constexpr size_t NE = (size_t)Mrows * Em;  // 4,194,304
constexpr size_t WE = (size_t)Em * Em;     // 1,048,576

// ---------------- f32 -> bf16 pre-convert (memory-bound) ----------------
__global__ __launch_bounds__(256) void convert_kernel(
    const float* __restrict__ q, const float* __restrict__ k,
    const float* __restrict__ v,
    const float* __restrict__ Wq, const float* __restrict__ Wk,
    const float* __restrict__ Wv, const float* __restrict__ Wo,
    short* __restrict__ qx, short* __restrict__ kx, short* __restrict__ vx,
    short* __restrict__ wqb, short* __restrict__ wkb,
    short* __restrict__ wvb, short* __restrict__ wob)
{
  const int seg = blockIdx.y;
  const float* src; short* dst; size_t n;
  switch (seg) {
    case 0: src = q;  dst = qx;  n = NE; break;
    case 1: src = k;  dst = kx;  n = NE; break;
    case 2: src = v;  dst = vx;  n = NE; break;
    case 3: src = Wq; dst = wqb; n = WE; break;
    case 4: src = Wk; dst = wkb; n = WE; break;
    case 5: src = Wv; dst = wvb; n = WE; break;
    default: src = Wo; dst = wob; n = WE; break;
  }
  const size_t i = ((size_t)blockIdx.x * 256 + threadIdx.x) * 8;
  if (i >= n) return;
  fx4 a = *(const fx4*)(src + i);
  fx4 b = *(const fx4*)(src + i + 4);
  bfx8 o = { f2bf(a[0]), f2bf(a[1]), f2bf(a[2]), f2bf(a[3]),
             f2bf(b[0]), f2bf(b[1]), f2bf(b[2]), f2bf(b[3]) };
  *(bfx8*)(dst + i) = o;
}

// ---------------- m97-structure bf16 GEMM, C^T orientation ----------------
// A-operand = W rows (features nn), B-operand = X rows (tokens m).
// Lane holds 4 consecutive nn at fixed token m => vector epilogue.
// Grid: blockIdx.x over M (32 values, fast axis -> XCD locality: each XCD
// gets 4 X-tiles + full W = ~3MB, L2-resident), blockIdx.y over N (8).

__global__ __launch_bounds__(256) void gemm_qkv_bf16(
    const short* __restrict__ qx, const short* __restrict__ kx,
    const short* __restrict__ vx,
    const short* __restrict__ Wqb, const short* __restrict__ Wkb,
    const short* __restrict__ Wvb,
    const float* __restrict__ bq, const float* __restrict__ bk,
    const float* __restrict__ bv,
    const float* __restrict__ pos,
    short* __restrict__ qb, short* __restrict__ kb, short* __restrict__ vb)
{
  __shared__ short As[128 * 32];   // W tile  (nn rows)
  __shared__ short Bs[128 * 32];   // X tile  (m rows)
  const int z = blockIdx.z;
  const short* X = (z == 0) ? qx : (z == 1) ? kx : vx;
  const short* W = (z == 0) ? Wqb : (z == 1) ? Wkb : Wvb;
  const float* bias = (z == 0) ? bq : (z == 1) ? bk : bv;
  short* dst = (z == 0) ? qb : (z == 1) ? kb : vb;

  const int m0 = blockIdx.x * 128;   // over Mrows (fast axis)
  const int n0 = blockIdx.y * 128;   // over Em
  const int t = threadIdx.x, lane = t & 63, wave = t >> 6;
  const int wr = wave >> 1, wc = wave & 1;
  const int fr = lane & 15, fq = lane >> 4;

  const int r0 = t >> 2, o0 = (t & 3) * 8;
  const int r1 = r0 + 64;
  short* lA0 = As + wave * 512;
  short* lA1 = As + 2048 + wave * 512;
  short* lB0 = Bs + wave * 512;
  short* lB1 = Bs + 2048 + wave * 512;

  fx4 acc[4][4] = {};

  for (int k0 = 0; k0 < Em; k0 += 32) {
    gld16(W + (size_t)(n0 + r0) * Em + k0 + o0, lA0);
    gld16(W + (size_t)(n0 + r1) * Em + k0 + o0, lA1);
    gld16(X + (size_t)(m0 + r0) * Em + k0 + o0, lB0);
    gld16(X + (size_t)(m0 + r1) * Em + k0 + o0, lB1);
    __syncthreads();

    bfx8 af[4], bf[4];
#pragma unroll
    for (int u = 0; u < 4; ++u)
      af[u] = *(const bfx8*)&As[(wr * 64 + u * 16 + fr) * 32 + fq * 8];
#pragma unroll
    for (int v = 0; v < 4; ++v)
      bf[v] = *(const bfx8*)&Bs[(wc * 64 + v * 16 + fr) * 32 + fq * 8];
#pragma unroll
    for (int u = 0; u < 4; ++u)
#pragma unroll
      for (int v = 0; v < 4; ++v)
        acc[u][v] = __builtin_amdgcn_mfma_f32_16x16x32_bf16(af[u], bf[v], acc[u][v], 0, 0, 0);
    __syncthreads();
  }

  // epilogue: D[nn][m]; lane holds 4 consecutive nn at fixed token m
#pragma unroll
  for (int u = 0; u < 4; ++u) {
    const int nn = n0 + wr * 64 + u * 16 + fq * 4;   // multiple of 4
    const int h = nn >> 6, d = nn & 63;
    const fx4 bb = *(const fx4*)&bias[nn];
#pragma unroll
    for (int v = 0; v < 4; ++v) {
      const int m = m0 + wc * 64 + v * 16 + fr;
      const int s = m & (Sq - 1), b = m >> 9;
      const fx4 pe = *(const fx4*)&pos[(size_t)s * Em + nn];
      const fx4 a = acc[u][v];
      if (z < 2) {
        bfx4 o = { f2bf(a[0] + bb[0] + pe[0]), f2bf(a[1] + bb[1] + pe[1]),
                   f2bf(a[2] + bb[2] + pe[2]), f2bf(a[3] + bb[3] + pe[3]) };
        *(bfx4*)&dst[(((size_t)b * Hn + h) * Sq + s) * Dh + d] = o;
      } else {
        // V transposed: [B,H,Dh,S]
        const size_t tb = ((size_t)b * Hn + h) * Dh;
#pragma unroll
        for (int i = 0; i < 4; ++i)
          dst[(tb + d + i) * Sq + s] = f2bf(a[i] + bb[i] + pe[i]);
      }
    }
  }
}

// output projection: out = wv @ Wo^T + bo  (f32 out, vector stores)
__global__ __launch_bounds__(256) void gemm_out_bf16(
    const short* __restrict__ wv, const short* __restrict__ Wob,
    const float* __restrict__ bo, float* __restrict__ out)
{
  __shared__ short As[128 * 32];
  __shared__ short Bs[128 * 32];

  const int m0 = blockIdx.x * 128;   // fast axis over M
  const int n0 = blockIdx.y * 128;
  const int t = threadIdx.x, lane = t & 63, wave = t >> 6;
  const int wr = wave >> 1, wc = wave & 1;
  const int fr = lane & 15, fq = lane >> 4;

  const int r0 = t >> 2, o0 = (t & 3) * 8;
  const int r1 = r0 + 64;
  short* lA0 = As + wave * 512;
  short* lA1 = As + 2048 + wave * 512;
  short* lB0 = Bs + wave * 512;
  short* lB1 = Bs + 2048 + wave * 512;

  fx4 acc[4][4] = {};

  for (int k0 = 0; k0 < Em; k0 += 32) {
    gld16(Wob + (size_t)(n0 + r0) * Em + k0 + o0, lA0);
    gld16(Wob + (size_t)(n0 + r1) * Em + k0 + o0, lA1);
    gld16(wv + (size_t)(m0 + r0) * Em + k0 + o0, lB0);
    gld16(wv + (size_t)(m0 + r1) * Em + k0 + o0, lB1);
    __syncthreads();

    bfx8 af[4], bf[4];
#pragma unroll
    for (int u = 0; u < 4; ++u)
      af[u] = *(const bfx8*)&As[(wr * 64 + u * 16 + fr) * 32 + fq * 8];
#pragma unroll
    for (int v = 0; v < 4; ++v)
      bf[v] = *(const bfx8*)&Bs[(wc * 64 + v * 16 + fr) * 32 + fq * 8];
#pragma unroll
    for (int u = 0; u < 4; ++u)
#pragma unroll
      for (int v = 0; v < 4; ++v)
        acc[u][v] = __builtin_amdgcn_mfma_f32_16x16x32_bf16(af[u], bf[v], acc[u][v], 0, 0, 0);
    __syncthreads();
  }

#pragma unroll
  for (int u = 0; u < 4; ++u) {
    const int nn = n0 + wr * 64 + u * 16 + fq * 4;
    const fx4 bb = *(const fx4*)&bo[nn];
#pragma unroll
    for (int v = 0; v < 4; ++v) {
      const int m = m0 + wc * 64 + v * 16 + fr;
      fx4 val = acc[u][v];
      val[0] += bb[0]; val[1] += bb[1]; val[2] += bb[2]; val[3] += bb[3];
      *(fx4*)&out[(size_t)m * Em + nn] = val;
    }
  }
}

// ---------------- Attention ----------------
// kb: [B,H,S,Dh]; vb: [B,H,Dh,S] (pre-transposed) -> V staging == K staging.
constexpr int KVB = 64, LDK = 72;

__global__ __launch_bounds__(256) void attn_kernel(
    const short* __restrict__ qb, const short* __restrict__ kb,
    const short* __restrict__ vb, short* __restrict__ wv)
{
  __shared__ short Ks[KVB * LDK];   // K tile [kv][d]
  __shared__ short Vt[Dh * LDK];    // V^T tile [d][kv]
  __shared__ short Ps[4][16 * LDK];

  const int bh = blockIdx.x;
  const int qt = blockIdx.y;
  const int t = threadIdx.x, lane = t & 63, wave = t >> 6;
  const int fr = lane & 15, fq = lane >> 4;

  const size_t base = (size_t)bh * Sq * Dh;
  const int q0 = qt * 64 + wave * 16;

  bfx8 qf[2];
  {
    const short* qp = qb + base + (size_t)(q0 + fr) * Dh;
    qf[0] = *(const bfx8*)(qp + fq * 8);
    qf[1] = *(const bfx8*)(qp + 32 + fq * 8);
  }

  float mrow[4] = { -1e30f, -1e30f, -1e30f, -1e30f };
  float lrow[4] = { 0.f, 0.f, 0.f, 0.f };
  fx4 oacc[4] = {};

  const int kr = t >> 2, kc = (t & 3) * 16;

  for (int kv0 = 0; kv0 < Sq; kv0 += KVB) {
    {  // stage K [64 kv][64 d]
      const short* kp = kb + base + (size_t)(kv0 + kr) * Dh + kc;
      bfx8 u0 = *(const bfx8*)kp;
      bfx8 u1 = *(const bfx8*)(kp + 8);
      *(bfx8*)&Ks[kr * LDK + kc] = u0;
      *(bfx8*)&Ks[kr * LDK + kc + 8] = u1;
    }
    {  // stage V^T [64 d][64 kv] straight from transposed global
      const short* vp = vb + base + (size_t)kr * Sq + kv0 + kc;
      bfx8 u0 = *(const bfx8*)vp;
      bfx8 u1 = *(const bfx8*)(vp + 8);
      *(bfx8*)&Vt[kr * LDK + kc] = u0;
      *(bfx8*)&Vt[kr * LDK + kc + 8] = u1;
    }
    __syncthreads();

    fx4 sa[4] = {};
#pragma unroll
    for (int nf = 0; nf < 4; ++nf) {
#pragma unroll
      for (int ks = 0; ks < 2; ++ks) {
        bfx8 kf = *(const bfx8*)&Ks[(nf * 16 + fr) * LDK + ks * 32 + fq * 8];
        sa[nf] = __builtin_amdgcn_mfma_f32_16x16x32_bf16(qf[ks], kf, sa[nf], 0, 0, 0);
      }
    }

#pragma unroll
    for (int i = 0; i < 4; ++i) {
      float mx = fmaxf(fmaxf(sa[0][i], sa[1][i]), fmaxf(sa[2][i], sa[3][i]));
      mx = fmaxf(mx, __shfl_xor(mx, 1));
      mx = fmaxf(mx, __shfl_xor(mx, 2));
      mx = fmaxf(mx, __shfl_xor(mx, 4));
      mx = fmaxf(mx, __shfl_xor(mx, 8));
      mx *= 0.125f;
      const float mn = fmaxf(mrow[i], mx);
      const float alpha = __expf(mrow[i] - mn);
      mrow[i] = mn;
      float rs = 0.f;
#pragma unroll
      for (int nf = 0; nf < 4; ++nf) {
        const float p = __expf(sa[nf][i] * 0.125f - mn);
        rs += p;
        Ps[wave][(fq * 4 + i) * LDK + nf * 16 + fr] = f2bf(p);
      }
      rs += __shfl_xor(rs, 1);
      rs += __shfl_xor(rs, 2);
      rs += __shfl_xor(rs, 4);
      rs += __shfl_xor(rs, 8);
      lrow[i] = lrow[i] * alpha + rs;
#pragma unroll
      for (int df = 0; df < 4; ++df) oacc[df][i] *= alpha;
    }
    __syncthreads();

    bfx8 pf[2];
    pf[0] = *(const bfx8*)&Ps[wave][fr * LDK + fq * 8];
    pf[1] = *(const bfx8*)&Ps[wave][fr * LDK + 32 + fq * 8];
#pragma unroll
    for (int df = 0; df < 4; ++df) {
#pragma unroll
      for (int ks = 0; ks < 2; ++ks) {
        bfx8 vf = *(const bfx8*)&Vt[(df * 16 + fr) * LDK + ks * 32 + fq * 8];
        oacc[df] = __builtin_amdgcn_mfma_f32_16x16x32_bf16(pf[ks], vf, oacc[df], 0, 0, 0);
      }
    }
    __syncthreads();
  }

  const int b = bh >> 4, h = bh & 15;
#pragma unroll
  for (int df = 0; df < 4; ++df) {
    const int d = df * 16 + fr;
#pragma unroll
    for (int i = 0; i < 4; ++i) {
      const int qrow = q0 + fq * 4 + i;
      const float o = oacc[df][i] / lrow[i];
      wv[((size_t)b * Sq + qrow) * Em + h * Dh + d] = f2bf(o);
    }
  }
}

extern "C" void kernel_launch(void* const* d_in, const int* in_sizes, int n_in,
                              void* d_out, int out_size, void* d_ws, size_t ws_size,
                              hipStream_t stream) {
  (void)in_sizes; (void)n_in; (void)out_size; (void)ws_size;
  const float* query = (const float*)d_in[0];
  const float* key   = (const float*)d_in[1];
  const float* value = (const float*)d_in[2];
  const float* Wq = (const float*)d_in[3];
  const float* bq = (const float*)d_in[4];
  const float* Wk = (const float*)d_in[5];
  const float* bk = (const float*)d_in[6];
  const float* Wv = (const float*)d_in[7];
  const float* bv = (const float*)d_in[8];
  const float* Wo = (const float*)d_in[9];
  const float* bo = (const float*)d_in[10];
  const float* pos = (const float*)d_in[11];

  short* qx = (short*)d_ws;
  short* kx = qx + NE;
  short* vx = kx + NE;
  short* Wqb = vx + NE;
  short* Wkb = Wqb + WE;
  short* Wvb = Wkb + WE;
  short* Wob = Wvb + WE;
  short* qb = Wob + WE;
  short* wv = qx;                 // alias: qx dead after gemm_qkv
  short* kb = (short*)d_out;      // d_out scratch, overwritten by gemm_out
  short* vb = kb + NE;            // [B,H,Dh,S]

  convert_kernel<<<dim3(2048, 7), 256, 0, stream>>>(
      query, key, value, Wq, Wk, Wv, Wo, qx, kx, vx, Wqb, Wkb, Wvb, Wob);
  gemm_qkv_bf16<<<dim3(Mrows / 128, Em / 128, 3), 256, 0, stream>>>(
      qx, kx, vx, Wqb, Wkb, Wvb, bq, bk, bv, pos, qb, kb, vb);
  attn_kernel<<<dim3(Bz * Hn, Sq / 64), 256, 0, stream>>>(qb, kb, vb, wv);
  gemm_out_bf16<<<dim3(Mrows / 128, Em / 128), 256, 0, stream>>>(
      wv, Wob, bo, (float*)d_out);
}

// Round 5
// 125.475 us; speedup vs baseline: 1.0684x; 1.0470x over previous
//
#include <hip/hip_runtime.h>
#include <hip/hip_bf16.h>

typedef __attribute__((ext_vector_type(8))) short bfx8;
typedef __attribute__((ext_vector_type(4))) short bfx4;
typedef __attribute__((ext_vector_type(4))) float fx4;

static __device__ __forceinline__ short f2bf(float f) {
  union { float f; unsigned u; } v; v.f = f;
  unsigned r = v.u + 0x7fffu + ((v.u >> 16) & 1u);
  return (short)(r >> 16);
}

static __device__ __forceinline__ void gld16(const void* g, void* l) {
  __builtin_amdgcn_global_load_lds(
      (const __attribute__((address_space(1))) void*)g,
      (__attribute__((address_space(3))) void*)l, 16, 0, 0);
}

constexpr int Bz = 8, Sq = 512, Em = 1024, Hn = 16, Dh = 64;
constexpr int Mrows = Bz * Sq;             // 4096
constexpr size_t NE = (size_t)Mrows * Em;  // 4,194,304
constexpr size_t WE = (size_t)Em * Em;     // 1,048,576

// ---------------- f32 -> bf16 pre-convert (memory-bound, exact flat grid) ----------------
__global__ __launch_bounds__(256) void convert_kernel(
    const float* __restrict__ q, const float* __restrict__ k,
    const float* __restrict__ v,
    const float* __restrict__ Wq, const float* __restrict__ Wk,
    const float* __restrict__ Wv, const float* __restrict__ Wo,
    short* __restrict__ qx, short* __restrict__ kx, short* __restrict__ vx,
    short* __restrict__ wqb, short* __restrict__ wkb,
    short* __restrict__ wvb, short* __restrict__ wob)
{
  const size_t c = (size_t)blockIdx.x * 256 + threadIdx.x;  // vec8 chunk id
  constexpr size_t CI = NE / 8;   // 524288 (block-aligned boundaries)
  constexpr size_t CW = WE / 8;   // 131072
  const float* src; short* dst; size_t off;
  if (c < 3 * CI) {
    const int sgi = (int)(c / CI);
    src = sgi == 0 ? q : sgi == 1 ? k : v;
    dst = sgi == 0 ? qx : sgi == 1 ? kx : vx;
    off = (c - (size_t)sgi * CI) * 8;
  } else {
    const size_t w = c - 3 * CI;
    const int sgi = (int)(w / CW);
    src = sgi == 0 ? Wq : sgi == 1 ? Wk : sgi == 2 ? Wv : Wo;
    dst = sgi == 0 ? wqb : sgi == 1 ? wkb : sgi == 2 ? wvb : wob;
    off = (w - (size_t)sgi * CW) * 8;
  }
  fx4 a = *(const fx4*)(src + off);
  fx4 b = *(const fx4*)(src + off + 4);
  bfx8 o = { f2bf(a[0]), f2bf(a[1]), f2bf(a[2]), f2bf(a[3]),
             f2bf(b[0]), f2bf(b[1]), f2bf(b[2]), f2bf(b[3]) };
  *(bfx8*)(dst + off) = o;
}

// ---------------- m97-structure bf16 GEMM, C^T orientation ----------------
// K-loop identical to R4 (verified). Epilogue: LDS-bounce -> coalesced stores.
// SM layout: K-loop uses SM[0:4096] as As, SM[4096:8192] as Bs;
// epilogue reuses all of SM as a 128x136 bf16 C-tile (34KB).
constexpr int LDP = 136;  // C-tile stride: 272B rows (16B-aligned, bank-spread)

__global__ __launch_bounds__(256) void gemm_qkv_bf16(
    const short* __restrict__ qx, const short* __restrict__ kx,
    const short* __restrict__ vx,
    const short* __restrict__ Wqb, const short* __restrict__ Wkb,
    const short* __restrict__ Wvb,
    const float* __restrict__ bq, const float* __restrict__ bk,
    const float* __restrict__ bv,
    const float* __restrict__ pos,
    short* __restrict__ qb, short* __restrict__ kb, short* __restrict__ vb)
{
  __shared__ short SM[128 * LDP];
  short* As = SM;
  short* Bs = SM + 4096;

  const int z = blockIdx.z;
  const short* X = (z == 0) ? qx : (z == 1) ? kx : vx;
  const short* W = (z == 0) ? Wqb : (z == 1) ? Wkb : Wvb;
  const float* bias = (z == 0) ? bq : (z == 1) ? bk : bv;
  short* dst = (z == 0) ? qb : (z == 1) ? kb : vb;

  const int m0 = blockIdx.x * 128;   // over Mrows (fast axis -> XCD locality)
  const int n0 = blockIdx.y * 128;   // over Em
  const int t = threadIdx.x, lane = t & 63, wave = t >> 6;
  const int wr = wave >> 1, wc = wave & 1;
  const int fr = lane & 15, fq = lane >> 4;

  const int r0 = t >> 2, o0 = (t & 3) * 8;
  const int r1 = r0 + 64;
  short* lA0 = As + wave * 512;
  short* lA1 = As + 2048 + wave * 512;
  short* lB0 = Bs + wave * 512;
  short* lB1 = Bs + 2048 + wave * 512;

  fx4 acc[4][4] = {};

  for (int k0 = 0; k0 < Em; k0 += 32) {
    gld16(W + (size_t)(n0 + r0) * Em + k0 + o0, lA0);
    gld16(W + (size_t)(n0 + r1) * Em + k0 + o0, lA1);
    gld16(X + (size_t)(m0 + r0) * Em + k0 + o0, lB0);
    gld16(X + (size_t)(m0 + r1) * Em + k0 + o0, lB1);
    __syncthreads();

    bfx8 af[4], bf[4];
#pragma unroll
    for (int u = 0; u < 4; ++u)
      af[u] = *(const bfx8*)&As[(wr * 64 + u * 16 + fr) * 32 + fq * 8];
#pragma unroll
    for (int v = 0; v < 4; ++v)
      bf[v] = *(const bfx8*)&Bs[(wc * 64 + v * 16 + fr) * 32 + fq * 8];
#pragma unroll
    for (int u = 0; u < 4; ++u)
#pragma unroll
      for (int v = 0; v < 4; ++v)
        acc[u][v] = __builtin_amdgcn_mfma_f32_16x16x32_bf16(af[u], bf[v], acc[u][v], 0, 0, 0);
    __syncthreads();
  }

  // ---- epilogue: +bias+pe, bounce through LDS, coalesced bfx8 stores ----
  const int rr = t >> 4, jj = t & 15;
  const int b = m0 >> 9;             // m0 % 512 + 127 < 512, so b uniform
  if (z < 2) {
    // C-tile [m][nn], readback rows m -> [B,H,S,Dh] (contiguous d)
#pragma unroll
    for (int u = 0; u < 4; ++u) {
      const int nn = wr * 64 + u * 16 + fq * 4;
      const int nng = n0 + nn;
      const fx4 bb = *(const fx4*)&bias[nng];
#pragma unroll
      for (int v = 0; v < 4; ++v) {
        const int m = wc * 64 + v * 16 + fr;
        const int s = (m0 + m) & (Sq - 1);
        const fx4 pe = *(const fx4*)&pos[(size_t)s * Em + nng];
        const fx4 a = acc[u][v];
        bfx4 o = { f2bf(a[0] + bb[0] + pe[0]), f2bf(a[1] + bb[1] + pe[1]),
                   f2bf(a[2] + bb[2] + pe[2]), f2bf(a[3] + bb[3] + pe[3]) };
        *(bfx4*)&SM[m * LDP + nn] = o;
      }
    }
    __syncthreads();
#pragma unroll
    for (int it = 0; it < 8; ++it) {
      const int m = it * 16 + rr;
      const int s = (m0 + m) & (Sq - 1);
      bfx8 val = *(const bfx8*)&SM[m * LDP + jj * 8];
      const int nng = n0 + jj * 8;
      const int h = nng >> 6, d = nng & 63;
      *(bfx8*)&dst[(((size_t)b * Hn + h) * Sq + s) * Dh + d] = val;
    }
  } else {
    // C-tile [nn][m^swz] (swz=(row&12)<<2: per-fq bank quartets, 8-runs kept)
    // readback rows nn -> V^T [B,H,Dh,S] (contiguous s)
#pragma unroll
    for (int u = 0; u < 4; ++u) {
      const int nnb = wr * 64 + u * 16 + fq * 4;
      const int nng = n0 + nnb;
      const fx4 bb = *(const fx4*)&bias[nng];
#pragma unroll
      for (int v = 0; v < 4; ++v) {
        const int m = wc * 64 + v * 16 + fr;
        const int s = (m0 + m) & (Sq - 1);
        const fx4 pe = *(const fx4*)&pos[(size_t)s * Em + nng];
        const fx4 a = acc[u][v];
#pragma unroll
        for (int i = 0; i < 4; ++i) {
          const int row = nnb + i;
          SM[row * LDP + (m ^ ((row & 12) << 2))] = f2bf(a[i] + bb[i] + pe[i]);
        }
      }
    }
    __syncthreads();
    const int s0 = m0 & (Sq - 1);
#pragma unroll
    for (int it = 0; it < 8; ++it) {
      const int row = it * 16 + rr;
      bfx8 val = *(const bfx8*)&SM[row * LDP + ((jj * 8) ^ ((row & 12) << 2))];
      const int nng = n0 + row;
      const int h = nng >> 6, d = nng & 63;
      *(bfx8*)&dst[(((size_t)b * Hn + h) * Dh + d) * Sq + s0 + jj * 8] = val;
    }
  }
}

// output projection: out = wv @ Wo^T + bo  (f32 out, vector stores)
__global__ __launch_bounds__(256) void gemm_out_bf16(
    const short* __restrict__ wv, const short* __restrict__ Wob,
    const float* __restrict__ bo, float* __restrict__ out)
{
  __shared__ short As[128 * 32];
  __shared__ short Bs[128 * 32];

  const int m0 = blockIdx.x * 128;   // fast axis over M
  const int n0 = blockIdx.y * 128;
  const int t = threadIdx.x, lane = t & 63, wave = t >> 6;
  const int wr = wave >> 1, wc = wave & 1;
  const int fr = lane & 15, fq = lane >> 4;

  const int r0 = t >> 2, o0 = (t & 3) * 8;
  const int r1 = r0 + 64;
  short* lA0 = As + wave * 512;
  short* lA1 = As + 2048 + wave * 512;
  short* lB0 = Bs + wave * 512;
  short* lB1 = Bs + 2048 + wave * 512;

  fx4 acc[4][4] = {};

  for (int k0 = 0; k0 < Em; k0 += 32) {
    gld16(Wob + (size_t)(n0 + r0) * Em + k0 + o0, lA0);
    gld16(Wob + (size_t)(n0 + r1) * Em + k0 + o0, lA1);
    gld16(wv + (size_t)(m0 + r0) * Em + k0 + o0, lB0);
    gld16(wv + (size_t)(m0 + r1) * Em + k0 + o0, lB1);
    __syncthreads();

    bfx8 af[4], bf[4];
#pragma unroll
    for (int u = 0; u < 4; ++u)
      af[u] = *(const bfx8*)&As[(wr * 64 + u * 16 + fr) * 32 + fq * 8];
#pragma unroll
    for (int v = 0; v < 4; ++v)
      bf[v] = *(const bfx8*)&Bs[(wc * 64 + v * 16 + fr) * 32 + fq * 8];
#pragma unroll
    for (int u = 0; u < 4; ++u)
#pragma unroll
      for (int v = 0; v < 4; ++v)
        acc[u][v] = __builtin_amdgcn_mfma_f32_16x16x32_bf16(af[u], bf[v], acc[u][v], 0, 0, 0);
    __syncthreads();
  }

#pragma unroll
  for (int u = 0; u < 4; ++u) {
    const int nn = n0 + wr * 64 + u * 16 + fq * 4;
    const fx4 bb = *(const fx4*)&bo[nn];
#pragma unroll
    for (int v = 0; v < 4; ++v) {
      const int m = m0 + wc * 64 + v * 16 + fr;
      fx4 val = acc[u][v];
      val[0] += bb[0]; val[1] += bb[1]; val[2] += bb[2]; val[3] += bb[3];
      *(fx4*)&out[(size_t)m * Em + nn] = val;
    }
  }
}

// ---------------- Attention ----------------
// kb: [B,H,S,Dh]; vb: [B,H,Dh,S] (pre-transposed) -> V staging == K staging.
constexpr int KVB = 64, LDK = 72;

__global__ __launch_bounds__(256) void attn_kernel(
    const short* __restrict__ qb, const short* __restrict__ kb,
    const short* __restrict__ vb, short* __restrict__ wv)
{
  __shared__ short Ks[KVB * LDK];   // K tile [kv][d]
  __shared__ short Vt[Dh * LDK];    // V^T tile [d][kv]
  __shared__ short Ps[4][16 * LDK];

  const int bh = blockIdx.x;
  const int qt = blockIdx.y;
  const int t = threadIdx.x, lane = t & 63, wave = t >> 6;
  const int fr = lane & 15, fq = lane >> 4;

  const size_t base = (size_t)bh * Sq * Dh;
  const int q0 = qt * 64 + wave * 16;

  bfx8 qf[2];
  {
    const short* qp = qb + base + (size_t)(q0 + fr) * Dh;
    qf[0] = *(const bfx8*)(qp + fq * 8);
    qf[1] = *(const bfx8*)(qp + 32 + fq * 8);
  }

  float mrow[4] = { -1e30f, -1e30f, -1e30f, -1e30f };
  float lrow[4] = { 0.f, 0.f, 0.f, 0.f };
  fx4 oacc[4] = {};

  const int kr = t >> 2, kc = (t & 3) * 16;

  for (int kv0 = 0; kv0 < Sq; kv0 += KVB) {
    {  // stage K [64 kv][64 d]
      const short* kp = kb + base + (size_t)(kv0 + kr) * Dh + kc;
      bfx8 u0 = *(const bfx8*)kp;
      bfx8 u1 = *(const bfx8*)(kp + 8);
      *(bfx8*)&Ks[kr * LDK + kc] = u0;
      *(bfx8*)&Ks[kr * LDK + kc + 8] = u1;
    }
    {  // stage V^T [64 d][64 kv] straight from transposed global
      const short* vp = vb + base + (size_t)kr * Sq + kv0 + kc;
      bfx8 u0 = *(const bfx8*)vp;
      bfx8 u1 = *(const bfx8*)(vp + 8);
      *(bfx8*)&Vt[kr * LDK + kc] = u0;
      *(bfx8*)&Vt[kr * LDK + kc + 8] = u1;
    }
    __syncthreads();

    fx4 sa[4] = {};
#pragma unroll
    for (int nf = 0; nf < 4; ++nf) {
#pragma unroll
      for (int ks = 0; ks < 2; ++ks) {
        bfx8 kf = *(const bfx8*)&Ks[(nf * 16 + fr) * LDK + ks * 32 + fq * 8];
        sa[nf] = __builtin_amdgcn_mfma_f32_16x16x32_bf16(qf[ks], kf, sa[nf], 0, 0, 0);
      }
    }

#pragma unroll
    for (int i = 0; i < 4; ++i) {
      float mx = fmaxf(fmaxf(sa[0][i], sa[1][i]), fmaxf(sa[2][i], sa[3][i]));
      mx = fmaxf(mx, __shfl_xor(mx, 1));
      mx = fmaxf(mx, __shfl_xor(mx, 2));
      mx = fmaxf(mx, __shfl_xor(mx, 4));
      mx = fmaxf(mx, __shfl_xor(mx, 8));
      mx *= 0.125f;
      const float mn = fmaxf(mrow[i], mx);
      const float alpha = __expf(mrow[i] - mn);
      mrow[i] = mn;
      float rs = 0.f;
#pragma unroll
      for (int nf = 0; nf < 4; ++nf) {
        const float p = __expf(sa[nf][i] * 0.125f - mn);
        rs += p;
        Ps[wave][(fq * 4 + i) * LDK + nf * 16 + fr] = f2bf(p);
      }
      rs += __shfl_xor(rs, 1);
      rs += __shfl_xor(rs, 2);
      rs += __shfl_xor(rs, 4);
      rs += __shfl_xor(rs, 8);
      lrow[i] = lrow[i] * alpha + rs;
#pragma unroll
      for (int df = 0; df < 4; ++df) oacc[df][i] *= alpha;
    }
    __syncthreads();

    bfx8 pf[2];
    pf[0] = *(const bfx8*)&Ps[wave][fr * LDK + fq * 8];
    pf[1] = *(const bfx8*)&Ps[wave][fr * LDK + 32 + fq * 8];
#pragma unroll
    for (int df = 0; df < 4; ++df) {
#pragma unroll
      for (int ks = 0; ks < 2; ++ks) {
        bfx8 vf = *(const bfx8*)&Vt[(df * 16 + fr) * LDK + ks * 32 + fq * 8];
        oacc[df] = __builtin_amdgcn_mfma_f32_16x16x32_bf16(pf[ks], vf, oacc[df], 0, 0, 0);
      }
    }
    __syncthreads();
  }

  const int b = bh >> 4, h = bh & 15;
#pragma unroll
  for (int df = 0; df < 4; ++df) {
    const int d = df * 16 + fr;
#pragma unroll
    for (int i = 0; i < 4; ++i) {
      const int qrow = q0 + fq * 4 + i;
      const float o = oacc[df][i] / lrow[i];
      wv[((size_t)b * Sq + qrow) * Em + h * Dh + d] = f2bf(o);
    }
  }
}

extern "C" void kernel_launch(void* const* d_in, const int* in_sizes, int n_in,
                              void* d_out, int out_size, void* d_ws, size_t ws_size,
                              hipStream_t stream) {
  (void)in_sizes; (void)n_in; (void)out_size; (void)ws_size;
  const float* query = (const float*)d_in[0];
  const float* key   = (const float*)d_in[1];
  const float* value = (const float*)d_in[2];
  const float* Wq = (const float*)d_in[3];
  const float* bq = (const float*)d_in[4];
  const float* Wk = (const float*)d_in[5];
  const float* bk = (const float*)d_in[6];
  const float* Wv = (const float*)d_in[7];
  const float* bv = (const float*)d_in[8];
  const float* Wo = (const float*)d_in[9];
  const float* bo = (const float*)d_in[10];
  const float* pos = (const float*)d_in[11];

  short* qx = (short*)d_ws;
  short* kx = qx + NE;
  short* vx = kx + NE;
  short* Wqb = vx + NE;
  short* Wkb = Wqb + WE;
  short* Wvb = Wkb + WE;
  short* Wob = Wvb + WE;
  short* qb = Wob + WE;
  short* wv = qx;                 // alias: qx dead after gemm_qkv
  short* kb = (short*)d_out;      // d_out scratch, overwritten by gemm_out
  short* vb = kb + NE;            // [B,H,Dh,S]

  convert_kernel<<<dim3(8192), 256, 0, stream>>>(
      query, key, value, Wq, Wk, Wv, Wo, qx, kx, vx, Wqb, Wkb, Wvb, Wob);
  gemm_qkv_bf16<<<dim3(Mrows / 128, Em / 128, 3), 256, 0, stream>>>(
      qx, kx, vx, Wqb, Wkb, Wvb, bq, bk, bv, pos, qb, kb, vb);
  attn_kernel<<<dim3(Bz * Hn, Sq / 64), 256, 0, stream>>>(qb, kb, vb, wv);
  gemm_out_bf16<<<dim3(Mrows / 128, Em / 128), 256, 0, stream>>>(
      wv, Wob, bo, (float*)d_out);
}